// Round 1
// 94.767 us; speedup vs baseline: 1.0310x; 1.0310x over previous
//
#include <hip/hip_runtime.h>

#define NPTS 512      // N rows
#define INS  512      // INSIZE
#define KDIM 64       // K groups
#define DDIM 16       // D per group
#define CDIM (KDIM*DDIM)  // 1024 output cols of the linear
#define OUTC (INS + KDIM) // 576

typedef __attribute__((ext_vector_type(4))) float f32x4;
typedef __attribute__((ext_vector_type(8))) short short8v;      // 8 bf16 MFMA frag
typedef __attribute__((ext_vector_type(4))) unsigned short u16x4;
typedef __attribute__((ext_vector_type(8))) unsigned short u16x8;

__device__ __forceinline__ float exp2_fast(float x) {
    return __builtin_amdgcn_exp2f(x);
}

// fp32 -> bf16 round-to-nearest-even
__device__ __forceinline__ unsigned short f2bf_rne(float f) {
    unsigned u = __float_as_uint(f);
    u += 0x7FFF + ((u >> 16) & 1);
    return (unsigned short)(u >> 16);
}
__device__ __forceinline__ float bf2f(unsigned short h) {
    return __uint_as_float(((unsigned)h) << 16);
}

// ---------------- Kernel 0: split x, W into bf16 hi + bf16 lo (exact residual).
// x: 65536 float4, W: 131072 float4 -> 768 blocks x 256 thr, 1 float4 each.
__global__ __launch_bounds__(256) void convert_kernel(
    const float* __restrict__ x, const float* __restrict__ W,
    unsigned short* __restrict__ xh, unsigned short* __restrict__ xl,
    unsigned short* __restrict__ wh, unsigned short* __restrict__ wl)
{
    const int gid = blockIdx.x * 256 + threadIdx.x;
    const float4* src;
    unsigned short *dh, *dl;
    int idx;
    if (gid < NPTS * INS / 4) {
        src = (const float4*)x; idx = gid; dh = xh; dl = xl;
    } else {
        src = (const float4*)W; idx = gid - NPTS * INS / 4; dh = wh; dl = wl;
    }
    float4 v = src[idx];
    u16x4 hv, lv;
    hv[0] = f2bf_rne(v.x); lv[0] = f2bf_rne(v.x - bf2f(hv[0]));
    hv[1] = f2bf_rne(v.y); lv[1] = f2bf_rne(v.y - bf2f(hv[1]));
    hv[2] = f2bf_rne(v.z); lv[2] = f2bf_rne(v.z - bf2f(hv[2]));
    hv[3] = f2bf_rne(v.w); lv[3] = f2bf_rne(v.w - bf2f(hv[3]));
    *(u16x4*)&dh[idx * 4] = hv;
    *(u16x4*)&dl[idx * 4] = lv;
}

// ---------------- Kernel A: split-bf16 MFMA GEMM, full K=512 in one pass.
// feat = (x @ W^T + b) * log2(e), stored featT[k][i][d].
// acc = xh*Wh + xh*Wl + xl*Wh  (lo*lo dropped: ~4e-6 abs err on feat).
// Tile 64i x 64c per block, 4 waves (2x2), each wave 32x32 = 2x2 16x16 frags.
// LDS stride 40 bf16 (80 B): rows 16B-aligned, frag ds_read_b128 hits
// bank-quad (5*row+g)%8 -> all 8 quads exactly 2x per 16 lanes = conflict-free.
#define BM 64
#define BN 64
#define BK 32
#define LDK 40

__global__ __launch_bounds__(256) void gemm_mfma_kernel(
    const unsigned short* __restrict__ xh, const unsigned short* __restrict__ xl,
    const unsigned short* __restrict__ wh, const unsigned short* __restrict__ wl,
    const float* __restrict__ bias,
    float* __restrict__ featT)      // [64][512][16]
{
    __shared__ unsigned short Ah[BM * LDK], Al[BM * LDK];
    __shared__ unsigned short Bh[BN * LDK], Bl[BN * LDK];

    const int tid   = threadIdx.x;
    const int cbase = blockIdx.x * BN;   // 16 c-tiles
    const int ibase = blockIdx.y * BM;   // 8 i-tiles

    const int lane = tid & 63;
    const int wv   = tid >> 6;
    const int wm   = wv >> 1;            // wave row 0..1
    const int wn   = wv & 1;             // wave col 0..1

    // staging: row = tid>>2 (0..63), k-chunk = (tid&3)*8 -> one u16x8 per array
    const int srow = tid >> 2;
    const int skg  = tid & 3;
    const size_t gA0 = (size_t)(ibase + srow) * INS + skg * 8;
    const size_t gB0 = (size_t)(cbase + srow) * INS + skg * 8;
    const int    loff = srow * LDK + skg * 8;

    // fragment addresses: A row = lane&15, k-slot group = lane>>4 (8 contiguous k)
    // (same bijective k-map for A and B -> result independent of HW k-grouping)
    const int frow  = lane & 15;
    const int fg    = lane >> 4;
    const int aoff  = (wm * 32 + frow) * LDK + fg * 8;
    const int boff  = (wn * 32 + frow) * LDK + fg * 8;

    f32x4 acc[2][2] = {};

    // register double-buffer: prefetch tile kt+1 while computing kt
    u16x8 ra = *(const u16x8*)&xh[gA0];
    u16x8 rl = *(const u16x8*)&xl[gA0];
    u16x8 rb = *(const u16x8*)&wh[gB0];
    u16x8 rc = *(const u16x8*)&wl[gB0];

    for (int kt = 0; kt < INS / BK; ++kt) {
        __syncthreads();   // previous tile's frag reads done
        *(u16x8*)&Ah[loff] = ra;
        *(u16x8*)&Al[loff] = rl;
        *(u16x8*)&Bh[loff] = rb;
        *(u16x8*)&Bl[loff] = rc;
        __syncthreads();
        if (kt + 1 < INS / BK) {
            const size_t o = (size_t)(kt + 1) * BK;
            ra = *(const u16x8*)&xh[gA0 + o];
            rl = *(const u16x8*)&xl[gA0 + o];
            rb = *(const u16x8*)&wh[gB0 + o];
            rc = *(const u16x8*)&wl[gB0 + o];
        }

        short8v ah[2], al[2], bh[2], bl[2];
        #pragma unroll
        for (int f = 0; f < 2; ++f) {
            ah[f] = *(const short8v*)&Ah[aoff + f * 16 * LDK];
            al[f] = *(const short8v*)&Al[aoff + f * 16 * LDK];
            bh[f] = *(const short8v*)&Bh[boff + f * 16 * LDK];
            bl[f] = *(const short8v*)&Bl[boff + f * 16 * LDK];
        }
        #pragma unroll
        for (int m = 0; m < 2; ++m) {
            #pragma unroll
            for (int n = 0; n < 2; ++n) {
                acc[m][n] = __builtin_amdgcn_mfma_f32_16x16x32_bf16(ah[m], bh[n], acc[m][n], 0, 0, 0);
                acc[m][n] = __builtin_amdgcn_mfma_f32_16x16x32_bf16(ah[m], bl[n], acc[m][n], 0, 0, 0);
                acc[m][n] = __builtin_amdgcn_mfma_f32_16x16x32_bf16(al[m], bh[n], acc[m][n], 0, 0, 0);
            }
        }
    }

    // epilogue: C/D layout col=lane&15 (c-dim), row=(lane>>4)*4+r (i-dim)  [HW-verified]
    const float LOG2E = 1.4426950408889634f;
    const int r0 = (lane >> 4) * 4;
    #pragma unroll
    for (int m = 0; m < 2; ++m) {
        const int i0 = ibase + wm * 32 + m * 16 + r0;
        #pragma unroll
        for (int n = 0; n < 2; ++n) {
            const int c  = cbase + wn * 32 + n * 16 + (lane & 15);
            const float bv = bias[c];
            const int kk = c >> 4;
            const int d  = c & 15;
            float* dst = featT + (size_t)kk * NPTS * DDIM + d;
            #pragma unroll
            for (int r = 0; r < 4; ++r) {
                dst[(size_t)(i0 + r) * DDIM] = (acc[m][n][r] + bv) * LOG2E;
            }
        }
    }
}

// ---------------- Kernel B: out[:, :512] = x ; out[:, 512:576] = -1.0
// (the -1 absorbs the diagonal's exp2(-0)=1; pairwise atomically accumulates on top)
__global__ __launch_bounds__(256) void init_out_kernel(
    const float* __restrict__ x, float* __restrict__ out)
{
    const int idx = blockIdx.x * 256 + threadIdx.x;  // 512 * 144 = 73728 float4
    const int i  = idx / (OUTC / 4);
    const int j4 = idx - i * (OUTC / 4);
    float4 v;
    if (j4 < INS / 4) {
        v = ((const float4*)x)[i * (INS / 4) + j4];
    } else {
        v = make_float4(-1.0f, -1.0f, -1.0f, -1.0f);
    }
    ((float4*)out)[idx] = v;
}

// ---------------- Kernel C: o_b accumulation (single featT buffer now).
// grid (64 k, 4 itile(128 i), 4 jq(128 j)) = 1024 blocks x 256 thr.
// Diagonal exactness: fi and fj read the identical memory -> diff == 0 bitwise.
__global__ __launch_bounds__(256, 4) void pairwise_kernel(
    const float* __restrict__ f0, float* __restrict__ out)   // out [512][576]
{
    const int k     = blockIdx.x;
    const int itile = blockIdx.y;
    const int jq    = blockIdx.z;

    __shared__ float fj[128 * DDIM];   // 8 KB: this block's j-slice
    __shared__ float part[4][128];

    // stage j-range [jq*128, +128): 512 float4, 2 per thread (plain copy)
    {
        const size_t base = ((size_t)k * NPTS + jq * 128) * DDIM;
        const float4* s0 = (const float4*)(f0 + base);
        float4* dst = (float4*)fj;
        dst[threadIdx.x]       = s0[threadIdx.x];
        dst[threadIdx.x + 256] = s0[threadIdx.x + 256];
    }

    const int lane = threadIdx.x & 63;
    const int wv   = threadIdx.x >> 6;
    const int i0   = itile * 128 + lane;
    const int i1   = i0 + 64;

    float fi0[16], fi1[16];
    {
        const float4* p0 = (const float4*)(f0 + ((size_t)k * NPTS + i0) * DDIM);
        const float4* p1 = (const float4*)(f0 + ((size_t)k * NPTS + i1) * DDIM);
        #pragma unroll
        for (int q = 0; q < 4; ++q) {
            float4 a = p0[q];
            fi0[q * 4 + 0] = a.x; fi0[q * 4 + 1] = a.y;
            fi0[q * 4 + 2] = a.z; fi0[q * 4 + 3] = a.w;
            float4 b = p1[q];
            fi1[q * 4 + 0] = b.x; fi1[q * 4 + 1] = b.y;
            fi1[q * 4 + 2] = b.z; fi1[q * 4 + 3] = b.w;
        }
    }
    __syncthreads();

    float acc0 = 0.f, acc1 = 0.f;
    const float* fp = fj + wv * 32 * DDIM;
    #pragma unroll 2
    for (int jj = 0; jj < 32; ++jj) {
        const float* p = fp + jj * DDIM;
        float4 q0 = *(const float4*)(p);
        float4 q1 = *(const float4*)(p + 4);
        float4 q2 = *(const float4*)(p + 8);
        float4 q3 = *(const float4*)(p + 12);
        // i0
        {
            float a0 = fabsf(fi0[0]  - q0.x) + fabsf(fi0[1]  - q0.y)
                     + fabsf(fi0[2]  - q0.z) + fabsf(fi0[3]  - q0.w);
            float a1 = fabsf(fi0[4]  - q1.x) + fabsf(fi0[5]  - q1.y)
                     + fabsf(fi0[6]  - q1.z) + fabsf(fi0[7]  - q1.w);
            float a2 = fabsf(fi0[8]  - q2.x) + fabsf(fi0[9]  - q2.y)
                     + fabsf(fi0[10] - q2.z) + fabsf(fi0[11] - q2.w);
            float a3 = fabsf(fi0[12] - q3.x) + fabsf(fi0[13] - q3.y)
                     + fabsf(fi0[14] - q3.z) + fabsf(fi0[15] - q3.w);
            acc0 += exp2_fast(-((a0 + a1) + (a2 + a3)));
        }
        // i1
        {
            float b0 = fabsf(fi1[0]  - q0.x) + fabsf(fi1[1]  - q0.y)
                     + fabsf(fi1[2]  - q0.z) + fabsf(fi1[3]  - q0.w);
            float b1 = fabsf(fi1[4]  - q1.x) + fabsf(fi1[5]  - q1.y)
                     + fabsf(fi1[6]  - q1.z) + fabsf(fi1[7]  - q1.w);
            float b2 = fabsf(fi1[8]  - q2.x) + fabsf(fi1[9]  - q2.y)
                     + fabsf(fi1[10] - q2.z) + fabsf(fi1[11] - q2.w);
            float b3 = fabsf(fi1[12] - q3.x) + fabsf(fi1[13] - q3.y)
                     + fabsf(fi1[14] - q3.z) + fabsf(fi1[15] - q3.w);
            acc1 += exp2_fast(-((b0 + b1) + (b2 + b3)));
        }
    }

    part[wv][lane]      = acc0;
    part[wv][lane + 64] = acc1;
    __syncthreads();

    if (threadIdx.x < 128) {
        float s = (part[0][threadIdx.x] + part[1][threadIdx.x])
                + (part[2][threadIdx.x] + part[3][threadIdx.x]);
        const int i = itile * 128 + threadIdx.x;
        atomicAdd(&out[(size_t)i * OUTC + INS + k], s);
    }
}

extern "C" void kernel_launch(void* const* d_in, const int* in_sizes, int n_in,
                              void* d_out, int out_size, void* d_ws, size_t ws_size,
                              hipStream_t stream) {
    const float* x    = (const float*)d_in[0];
    const float* W    = (const float*)d_in[1];
    const float* bias = (const float*)d_in[2];
    float* out = (float*)d_out;

    // workspace layout (5 MB total):
    // [0, 2MB)   featT  [64][512][16] fp32
    // [2, 2.5MB) xh     [512][512] bf16
    // [2.5, 3MB) xl
    // [3, 4MB)   wh     [1024][512] bf16
    // [4, 5MB)   wl
    float* featT = (float*)d_ws;
    unsigned short* xh = (unsigned short*)((char*)d_ws + (size_t)(2 << 20));
    unsigned short* xl = xh + (size_t)NPTS * INS;
    unsigned short* wh = xl + (size_t)NPTS * INS;
    unsigned short* wl = wh + (size_t)CDIM * INS;

    convert_kernel<<<dim3((NPTS * INS / 4 + CDIM * INS / 4) / 256), 256, 0, stream>>>(
        x, W, xh, xl, wh, wl);
    gemm_mfma_kernel<<<dim3(CDIM / BN, NPTS / BM), 256, 0, stream>>>(
        xh, xl, wh, wl, bias, featT);
    init_out_kernel<<<dim3(NPTS * (OUTC / 4) / 256), 256, 0, stream>>>(x, out);
    pairwise_kernel<<<dim3(KDIM, 4, 4), 256, 0, stream>>>(featT, out);
}

// Round 2
// 91.249 us; speedup vs baseline: 1.0707x; 1.0386x over previous
//
#include <hip/hip_runtime.h>

#define NPTS 512      // N rows
#define INS  512      // INSIZE
#define KDIM 64       // K groups
#define DDIM 16       // D per group
#define CDIM (KDIM*DDIM)  // 1024 output cols of the linear
#define OUTC (INS + KDIM) // 576

typedef __attribute__((ext_vector_type(4))) float f32x4;
typedef __attribute__((ext_vector_type(8))) short short8v;      // 8 bf16 MFMA frag
typedef __attribute__((ext_vector_type(4))) unsigned short u16x4;
typedef __attribute__((ext_vector_type(8))) unsigned short u16x8;

__device__ __forceinline__ float exp2_fast(float x) {
    return __builtin_amdgcn_exp2f(x);
}

// fp32 -> bf16 round-to-nearest-even
__device__ __forceinline__ unsigned short f2bf_rne(float f) {
    unsigned u = __float_as_uint(f);
    u += 0x7FFF + ((u >> 16) & 1);
    return (unsigned short)(u >> 16);
}
__device__ __forceinline__ float bf2f(unsigned short h) {
    return __uint_as_float(((unsigned)h) << 16);
}

// ---------------- Kernel 0: split x, W into bf16 hi + lo AND copy x into out[:, :512].
// blocks 0..767: conversion (x: 256 blocks, W: 512 blocks). blocks 768..1023: x-copy.
__global__ __launch_bounds__(256) void convert_kernel(
    const float* __restrict__ x, const float* __restrict__ W,
    float* __restrict__ out,
    unsigned short* __restrict__ xh, unsigned short* __restrict__ xl,
    unsigned short* __restrict__ wh, unsigned short* __restrict__ wl)
{
    const int b = blockIdx.x;
    const int tid = threadIdx.x;
    if (b < 768) {
        const int gid = b * 256 + tid;
        const float4* src;
        unsigned short *dh, *dl;
        int idx;
        if (gid < NPTS * INS / 4) {
            src = (const float4*)x; idx = gid; dh = xh; dl = xl;
        } else {
            src = (const float4*)W; idx = gid - NPTS * INS / 4; dh = wh; dl = wl;
        }
        float4 v = src[idx];
        u16x4 hv, lv;
        hv[0] = f2bf_rne(v.x); lv[0] = f2bf_rne(v.x - bf2f(hv[0]));
        hv[1] = f2bf_rne(v.y); lv[1] = f2bf_rne(v.y - bf2f(hv[1]));
        hv[2] = f2bf_rne(v.z); lv[2] = f2bf_rne(v.z - bf2f(hv[2]));
        hv[3] = f2bf_rne(v.w); lv[3] = f2bf_rne(v.w - bf2f(hv[3]));
        *(u16x4*)&dh[idx * 4] = hv;
        *(u16x4*)&dl[idx * 4] = lv;
    } else {
        // out[:, :512] = x  (row pitch 576 floats = 144 float4, 16B-aligned)
        const int idx = (b - 768) * 256 + tid;   // 0 .. 65535
        const int i  = idx >> 7;                 // /128
        const int j4 = idx & 127;
        ((float4*)out)[i * (OUTC / 4) + j4] = ((const float4*)x)[i * (INS / 4) + j4];
    }
}

// ---------------- Kernel A: split-bf16 MFMA GEMM, full K=512.
// acc = xh*Wh + xh*Wl + xl*Wh  (lo*lo dropped).
// Tile 32i x 64c, grid 16x16 = 256 blocks (1/CU). 4 waves: 2(m) x 2(n),
// wave tile 16x32 = 1x2 16x16 frags. LDK=40: frag ds_read_b128 bank-quad
// (5*row+g)%8 -> 2-way within quarter-wave = conflict-free.
#define BM 32
#define BN 64
#define BK 32
#define LDK 40

__global__ __launch_bounds__(256) void gemm_mfma_kernel(
    const unsigned short* __restrict__ xh, const unsigned short* __restrict__ xl,
    const unsigned short* __restrict__ wh, const unsigned short* __restrict__ wl,
    const float* __restrict__ bias,
    float* __restrict__ featT)      // [64][512][16]
{
    __shared__ unsigned short Ah[BM * LDK], Al[BM * LDK];
    __shared__ unsigned short Bh[BN * LDK], Bl[BN * LDK];

    const int tid   = threadIdx.x;
    const int cbase = blockIdx.x * BN;   // 16 c-tiles
    const int ibase = blockIdx.y * BM;   // 16 i-tiles

    const int lane = tid & 63;
    const int wv   = tid >> 6;
    const int wm   = wv >> 1;            // wave row 0..1 (16 i each)
    const int wn   = wv & 1;             // wave col 0..1 (32 c each)

    // staging: A by threads 0..127 (row=(tid&127)>>2, kg=tid&3); B by all 256.
    const int arow = (tid & 127) >> 2;   // 0..31
    const int brow = tid >> 2;           // 0..63
    const int kg   = tid & 3;
    const bool doA = (tid < 128);
    const size_t gA0 = (size_t)(ibase + arow) * INS + kg * 8;
    const size_t gB0 = (size_t)(cbase + brow) * INS + kg * 8;
    const int aloff = arow * LDK + kg * 8;
    const int bloff = brow * LDK + kg * 8;

    // fragment addresses (A/B share the k-slot bijection -> k-grouping cancels)
    const int frow = lane & 15;
    const int fg   = lane >> 4;
    const int aoff = (wm * 16 + frow) * LDK + fg * 8;
    const int boff = (wn * 32 + frow) * LDK + fg * 8;

    f32x4 acc[2] = {};

    u16x8 rah, ral, rbh, rbl;
    if (doA) { rah = *(const u16x8*)&xh[gA0]; ral = *(const u16x8*)&xl[gA0]; }
    rbh = *(const u16x8*)&wh[gB0];
    rbl = *(const u16x8*)&wl[gB0];

    for (int kt = 0; kt < INS / BK; ++kt) {
        __syncthreads();   // previous tile's frag reads done
        if (doA) { *(u16x8*)&Ah[aloff] = rah; *(u16x8*)&Al[aloff] = ral; }
        *(u16x8*)&Bh[bloff] = rbh;
        *(u16x8*)&Bl[bloff] = rbl;
        __syncthreads();
        if (kt + 1 < INS / BK) {
            const size_t o = (size_t)(kt + 1) * BK;
            if (doA) { rah = *(const u16x8*)&xh[gA0 + o]; ral = *(const u16x8*)&xl[gA0 + o]; }
            rbh = *(const u16x8*)&wh[gB0 + o];
            rbl = *(const u16x8*)&wl[gB0 + o];
        }

        short8v av_h = *(const short8v*)&Ah[aoff];
        short8v av_l = *(const short8v*)&Al[aoff];
        #pragma unroll
        for (int n = 0; n < 2; ++n) {
            short8v bv_h = *(const short8v*)&Bh[boff + n * 16 * LDK];
            short8v bv_l = *(const short8v*)&Bl[boff + n * 16 * LDK];
            acc[n] = __builtin_amdgcn_mfma_f32_16x16x32_bf16(av_h, bv_h, acc[n], 0, 0, 0);
            acc[n] = __builtin_amdgcn_mfma_f32_16x16x32_bf16(av_h, bv_l, acc[n], 0, 0, 0);
            acc[n] = __builtin_amdgcn_mfma_f32_16x16x32_bf16(av_l, bv_h, acc[n], 0, 0, 0);
        }
    }

    // epilogue: C/D layout col=lane&15 (c-dim), row=(lane>>4)*4+r (i-dim)  [HW-verified]
    const float LOG2E = 1.4426950408889634f;
    const int r0 = (lane >> 4) * 4;
    const int i0 = ibase + wm * 16 + r0;
    #pragma unroll
    for (int n = 0; n < 2; ++n) {
        const int c  = cbase + wn * 32 + n * 16 + (lane & 15);
        const float bv = bias[c];
        const int kk = c >> 4;
        const int d  = c & 15;
        float* dst = featT + (size_t)kk * NPTS * DDIM + d;
        #pragma unroll
        for (int r = 0; r < 4; ++r) {
            dst[(size_t)(i0 + r) * DDIM] = (acc[n][r] + bv) * LOG2E;
        }
    }
}

// ---------------- Kernel C: o_b. One block per (k, itile): 1024 thr = 16 waves,
// full 512-j sweep in-block -> plain stores, no atomics, no init.
// Wave wv sweeps j in [wv*32, +32) through a WAVE-UNIFORM pointer (scalar/broadcast
// loads on the SMEM/VMEM pipe -> LDS pipe freed; VALU-bound ~7.3 us).
// Diagonal: fi and the j-row read identical memory -> diff bitwise 0 -> exp2(0)=1,
// removed exactly by the final -1.0f.
__global__ __launch_bounds__(1024, 4) void pairwise_kernel(
    const float* __restrict__ f, float* __restrict__ out)   // out [512][576]
{
    const int k     = blockIdx.x;   // 64
    const int itile = blockIdx.y;   // 4

    __shared__ float part[16][128];

    const int tid  = threadIdx.x;
    const int lane = tid & 63;
    const int wv   = __builtin_amdgcn_readfirstlane(tid >> 6);  // 0..15, SGPR
    const int i0   = itile * 128 + lane;
    const int i1   = i0 + 64;

    float fi0[16], fi1[16];
    {
        const float4* p0 = (const float4*)(f + ((size_t)k * NPTS + i0) * DDIM);
        const float4* p1 = (const float4*)(f + ((size_t)k * NPTS + i1) * DDIM);
        #pragma unroll
        for (int q = 0; q < 4; ++q) {
            float4 a = p0[q];
            fi0[q * 4 + 0] = a.x; fi0[q * 4 + 1] = a.y;
            fi0[q * 4 + 2] = a.z; fi0[q * 4 + 3] = a.w;
            float4 b = p1[q];
            fi1[q * 4 + 0] = b.x; fi1[q * 4 + 1] = b.y;
            fi1[q * 4 + 2] = b.z; fi1[q * 4 + 3] = b.w;
        }
    }

    // wave-uniform j-row pointer
    const float* __restrict__ jrow = f + ((size_t)k * NPTS + wv * 32) * DDIM;

    float acc0 = 0.f, acc1 = 0.f;
    #pragma unroll 2
    for (int jj = 0; jj < 32; ++jj) {
        const float* p = jrow + jj * DDIM;   // uniform address
        float4 q0 = *(const float4*)(p);
        float4 q1 = *(const float4*)(p + 4);
        float4 q2 = *(const float4*)(p + 8);
        float4 q3 = *(const float4*)(p + 12);
        // i0
        {
            float a0 = fabsf(fi0[0]  - q0.x) + fabsf(fi0[1]  - q0.y)
                     + fabsf(fi0[2]  - q0.z) + fabsf(fi0[3]  - q0.w);
            float a1 = fabsf(fi0[4]  - q1.x) + fabsf(fi0[5]  - q1.y)
                     + fabsf(fi0[6]  - q1.z) + fabsf(fi0[7]  - q1.w);
            float a2 = fabsf(fi0[8]  - q2.x) + fabsf(fi0[9]  - q2.y)
                     + fabsf(fi0[10] - q2.z) + fabsf(fi0[11] - q2.w);
            float a3 = fabsf(fi0[12] - q3.x) + fabsf(fi0[13] - q3.y)
                     + fabsf(fi0[14] - q3.z) + fabsf(fi0[15] - q3.w);
            acc0 += exp2_fast(-((a0 + a1) + (a2 + a3)));
        }
        // i1
        {
            float b0 = fabsf(fi1[0]  - q0.x) + fabsf(fi1[1]  - q0.y)
                     + fabsf(fi1[2]  - q0.z) + fabsf(fi1[3]  - q0.w);
            float b1 = fabsf(fi1[4]  - q1.x) + fabsf(fi1[5]  - q1.y)
                     + fabsf(fi1[6]  - q1.z) + fabsf(fi1[7]  - q1.w);
            float b2 = fabsf(fi1[8]  - q2.x) + fabsf(fi1[9]  - q2.y)
                     + fabsf(fi1[10] - q2.z) + fabsf(fi1[11] - q2.w);
            float b3 = fabsf(fi1[12] - q3.x) + fabsf(fi1[13] - q3.y)
                     + fabsf(fi1[14] - q3.z) + fabsf(fi1[15] - q3.w);
            acc1 += exp2_fast(-((b0 + b1) + (b2 + b3)));
        }
    }

    part[wv][lane]      = acc0;
    part[wv][lane + 64] = acc1;
    __syncthreads();

    if (tid < 128) {
        float s = (((part[0][tid]  + part[1][tid])  + (part[2][tid]  + part[3][tid]))
                +  ((part[4][tid]  + part[5][tid])  + (part[6][tid]  + part[7][tid])))
                + (((part[8][tid]  + part[9][tid])  + (part[10][tid] + part[11][tid]))
                +  ((part[12][tid] + part[13][tid]) + (part[14][tid] + part[15][tid])));
        const int i = itile * 128 + tid;
        out[(size_t)i * OUTC + INS + k] = s - 1.0f;   // -1 removes the diagonal exactly
    }
}

extern "C" void kernel_launch(void* const* d_in, const int* in_sizes, int n_in,
                              void* d_out, int out_size, void* d_ws, size_t ws_size,
                              hipStream_t stream) {
    const float* x    = (const float*)d_in[0];
    const float* W    = (const float*)d_in[1];
    const float* bias = (const float*)d_in[2];
    float* out = (float*)d_out;

    // workspace layout (5 MB total):
    // [0, 2MB)   featT  [64][512][16] fp32
    // [2, 2.5MB) xh     [512][512] bf16
    // [2.5, 3MB) xl
    // [3, 4MB)   wh     [1024][512] bf16
    // [4, 5MB)   wl
    float* featT = (float*)d_ws;
    unsigned short* xh = (unsigned short*)((char*)d_ws + (size_t)(2 << 20));
    unsigned short* xl = xh + (size_t)NPTS * INS;
    unsigned short* wh = xl + (size_t)NPTS * INS;
    unsigned short* wl = wh + (size_t)CDIM * INS;

    convert_kernel<<<dim3(1024), 256, 0, stream>>>(x, W, out, xh, xl, wh, wl);
    gemm_mfma_kernel<<<dim3(CDIM / BN, NPTS / BM), 256, 0, stream>>>(
        xh, xl, wh, wl, bias, featT);
    pairwise_kernel<<<dim3(KDIM, 4), 1024, 0, stream>>>(featT, out);
}

// Round 3
// 90.076 us; speedup vs baseline: 1.0847x; 1.0130x over previous
//
#include <hip/hip_runtime.h>

#define NPTS 512      // N rows
#define INS  512      // INSIZE
#define KDIM 64       // K groups
#define DDIM 16       // D per group
#define CDIM (KDIM*DDIM)  // 1024 output cols of the linear
#define OUTC (INS + KDIM) // 576

typedef __attribute__((ext_vector_type(4))) float f32x4;
typedef __attribute__((ext_vector_type(8))) short short8v;      // 8 bf16 MFMA frag
typedef __attribute__((ext_vector_type(4))) unsigned short u16x4;
typedef __attribute__((ext_vector_type(8))) unsigned short u16x8;

__device__ __forceinline__ float exp2_fast(float x) {
    return __builtin_amdgcn_exp2f(x);
}

// fp32 -> bf16 round-to-nearest-even
__device__ __forceinline__ unsigned short f2bf_rne(float f) {
    unsigned u = __float_as_uint(f);
    u += 0x7FFF + ((u >> 16) & 1);
    return (unsigned short)(u >> 16);
}
__device__ __forceinline__ float bf2f(unsigned short h) {
    return __uint_as_float(((unsigned)h) << 16);
}

// ---------------- Kernel 0: bf16 hi/lo split of x,W + out init.
// b <  256 : x  -> xh, xl          (65536 float4)
// b <  768 : W  -> wh, wl          (131072 float4)
// b < 1024 : out[:, :512] = x      (65536 float4)
// b < 1056 : out[:, 512:576] = -1  (8192 float4)  [-1 removes the exact diagonal e=1]
__global__ __launch_bounds__(256) void convert_kernel(
    const float* __restrict__ x, const float* __restrict__ W,
    float* __restrict__ out,
    unsigned short* __restrict__ xh, unsigned short* __restrict__ xl,
    unsigned short* __restrict__ wh, unsigned short* __restrict__ wl)
{
    const int b = blockIdx.x;
    const int tid = threadIdx.x;
    if (b < 768) {
        const int gid = b * 256 + tid;
        const float4* src;
        unsigned short *dh, *dl;
        int idx;
        if (gid < NPTS * INS / 4) {
            src = (const float4*)x; idx = gid; dh = xh; dl = xl;
        } else {
            src = (const float4*)W; idx = gid - NPTS * INS / 4; dh = wh; dl = wl;
        }
        float4 v = src[idx];
        u16x4 hv, lv;
        hv[0] = f2bf_rne(v.x); lv[0] = f2bf_rne(v.x - bf2f(hv[0]));
        hv[1] = f2bf_rne(v.y); lv[1] = f2bf_rne(v.y - bf2f(hv[1]));
        hv[2] = f2bf_rne(v.z); lv[2] = f2bf_rne(v.z - bf2f(hv[2]));
        hv[3] = f2bf_rne(v.w); lv[3] = f2bf_rne(v.w - bf2f(hv[3]));
        *(u16x4*)&dh[idx * 4] = hv;
        *(u16x4*)&dl[idx * 4] = lv;
    } else if (b < 1024) {
        const int idx = (b - 768) * 256 + tid;   // 0 .. 65535
        const int i  = idx >> 7;                 // /128
        const int j4 = idx & 127;
        ((float4*)out)[i * (OUTC / 4) + j4] = ((const float4*)x)[i * (INS / 4) + j4];
    } else {
        const int idx = (b - 1024) * 256 + tid;  // 0 .. 8191
        const int i  = idx >> 4;                 // 16 float4 of o_b per row
        const int c4 = idx & 15;
        ((float4*)out)[i * (OUTC / 4) + INS / 4 + c4] =
            make_float4(-1.0f, -1.0f, -1.0f, -1.0f);
    }
}

// ---------------- Kernel A: split-bf16 MFMA GEMM, full K=512.
// acc = xh*Wh + xh*Wl + xl*Wh  (lo*lo dropped).
// Tile 32i x 64c, grid 16x16 = 256 blocks (1/CU). 4 waves: 2(m) x 2(n),
// wave tile 16x32 = 1x2 16x16 frags. LDK=40: frag ds_read_b128 bank-quad
// (5*row+g)%8 -> conflict-free.
#define BM 32
#define BN 64
#define BK 32
#define LDK 40

__global__ __launch_bounds__(256) void gemm_mfma_kernel(
    const unsigned short* __restrict__ xh, const unsigned short* __restrict__ xl,
    const unsigned short* __restrict__ wh, const unsigned short* __restrict__ wl,
    const float* __restrict__ bias,
    float* __restrict__ featT)      // [64][512][16]
{
    __shared__ unsigned short Ah[BM * LDK], Al[BM * LDK];
    __shared__ unsigned short Bh[BN * LDK], Bl[BN * LDK];

    const int tid   = threadIdx.x;
    const int cbase = blockIdx.x * BN;   // 16 c-tiles
    const int ibase = blockIdx.y * BM;   // 16 i-tiles

    const int lane = tid & 63;
    const int wv   = tid >> 6;
    const int wm   = wv >> 1;            // wave row 0..1 (16 i each)
    const int wn   = wv & 1;             // wave col 0..1 (32 c each)

    const int arow = (tid & 127) >> 2;   // 0..31
    const int brow = tid >> 2;           // 0..63
    const int kg   = tid & 3;
    const bool doA = (tid < 128);
    const size_t gA0 = (size_t)(ibase + arow) * INS + kg * 8;
    const size_t gB0 = (size_t)(cbase + brow) * INS + kg * 8;
    const int aloff = arow * LDK + kg * 8;
    const int bloff = brow * LDK + kg * 8;

    const int frow = lane & 15;
    const int fg   = lane >> 4;
    const int aoff = (wm * 16 + frow) * LDK + fg * 8;
    const int boff = (wn * 32 + frow) * LDK + fg * 8;

    f32x4 acc[2] = {};

    u16x8 rah, ral, rbh, rbl;
    if (doA) { rah = *(const u16x8*)&xh[gA0]; ral = *(const u16x8*)&xl[gA0]; }
    rbh = *(const u16x8*)&wh[gB0];
    rbl = *(const u16x8*)&wl[gB0];

    for (int kt = 0; kt < INS / BK; ++kt) {
        __syncthreads();   // previous tile's frag reads done
        if (doA) { *(u16x8*)&Ah[aloff] = rah; *(u16x8*)&Al[aloff] = ral; }
        *(u16x8*)&Bh[bloff] = rbh;
        *(u16x8*)&Bl[bloff] = rbl;
        __syncthreads();
        if (kt + 1 < INS / BK) {
            const size_t o = (size_t)(kt + 1) * BK;
            if (doA) { rah = *(const u16x8*)&xh[gA0 + o]; ral = *(const u16x8*)&xl[gA0 + o]; }
            rbh = *(const u16x8*)&wh[gB0 + o];
            rbl = *(const u16x8*)&wl[gB0 + o];
        }

        short8v av_h = *(const short8v*)&Ah[aoff];
        short8v av_l = *(const short8v*)&Al[aoff];
        #pragma unroll
        for (int n = 0; n < 2; ++n) {
            short8v bv_h = *(const short8v*)&Bh[boff + n * 16 * LDK];
            short8v bv_l = *(const short8v*)&Bl[boff + n * 16 * LDK];
            acc[n] = __builtin_amdgcn_mfma_f32_16x16x32_bf16(av_h, bv_h, acc[n], 0, 0, 0);
            acc[n] = __builtin_amdgcn_mfma_f32_16x16x32_bf16(av_h, bv_l, acc[n], 0, 0, 0);
            acc[n] = __builtin_amdgcn_mfma_f32_16x16x32_bf16(av_l, bv_h, acc[n], 0, 0, 0);
        }
    }

    // epilogue: C/D layout col=lane&15 (c-dim), row=(lane>>4)*4+r (i-dim)  [HW-verified]
    const float LOG2E = 1.4426950408889634f;
    const int r0 = (lane >> 4) * 4;
    const int i0 = ibase + wm * 16 + r0;
    #pragma unroll
    for (int n = 0; n < 2; ++n) {
        const int c  = cbase + wn * 32 + n * 16 + (lane & 15);
        const float bv = bias[c];
        const int kk = c >> 4;
        const int d  = c & 15;
        float* dst = featT + (size_t)kk * NPTS * DDIM + d;
        #pragma unroll
        for (int r = 0; r < 4; ++r) {
            dst[(size_t)(i0 + r) * DDIM] = (acc[n][r] + bv) * LOG2E;
        }
    }
}

// ---------------- Kernel C: o_b via SYMMETRIC triangular tiling.
// Grid (64 k, 10 tiles) x 512 thr. 128x128 tiles over (i,j):
//   tz 0..3 : diagonal (ti==tj), full tile, row sums only.
//   tz 4..9 : off-diagonal (ti<tj), each e_ij computed ONCE:
//             row sum (i, in-lane) + col sum (j, 6-step shfl_xor butterfly).
// Lane owns i = ti*128 + lane and +64; wave wv sweeps 16 j's via a
// wave-uniform pointer (scalar/broadcast loads, LDS pipe stays idle).
// Diagonal pair: fi and jrow read identical memory -> diff bitwise 0 ->
// exp2(0)=1, removed exactly by the -1.0 init.
__global__ __launch_bounds__(512) void pairwise_kernel(
    const float* __restrict__ f, float* __restrict__ out)   // out [512][576]
{
    const int k  = blockIdx.x;   // 64
    const int tz = blockIdx.y;   // 10
    const int ti = (int)((0x2110003210ULL >> (4 * tz)) & 0xF);
    const int tj = (int)((0x3323213210ULL >> (4 * tz)) & 0xF);
    const bool offdiag = (tz >= 4);

    __shared__ float part[8][128];
    __shared__ float colLds[128];

    const int tid  = threadIdx.x;
    const int lane = tid & 63;
    const int wv   = __builtin_amdgcn_readfirstlane(tid >> 6);  // 0..7, SGPR
    const int i0   = ti * 128 + lane;
    const int i1   = i0 + 64;

    float fi0[16], fi1[16];
    {
        const float4* p0 = (const float4*)(f + ((size_t)k * NPTS + i0) * DDIM);
        const float4* p1 = (const float4*)(f + ((size_t)k * NPTS + i1) * DDIM);
        #pragma unroll
        for (int q = 0; q < 4; ++q) {
            float4 a = p0[q];
            fi0[q * 4 + 0] = a.x; fi0[q * 4 + 1] = a.y;
            fi0[q * 4 + 2] = a.z; fi0[q * 4 + 3] = a.w;
            float4 b = p1[q];
            fi1[q * 4 + 0] = b.x; fi1[q * 4 + 1] = b.y;
            fi1[q * 4 + 2] = b.z; fi1[q * 4 + 3] = b.w;
        }
    }

    // wave-uniform j-row pointer: 16 j's per wave
    const float* __restrict__ jrow = f + ((size_t)k * NPTS + tj * 128 + wv * 16) * DDIM;

    float acc0 = 0.f, acc1 = 0.f;
    float colacc[16];
    #pragma unroll
    for (int jj = 0; jj < 16; ++jj) {
        const float* p = jrow + jj * DDIM;   // uniform address
        float4 q0 = *(const float4*)(p);
        float4 q1 = *(const float4*)(p + 4);
        float4 q2 = *(const float4*)(p + 8);
        float4 q3 = *(const float4*)(p + 12);
        float e0, e1;
        {
            float a0 = fabsf(fi0[0]  - q0.x) + fabsf(fi0[1]  - q0.y)
                     + fabsf(fi0[2]  - q0.z) + fabsf(fi0[3]  - q0.w);
            float a1 = fabsf(fi0[4]  - q1.x) + fabsf(fi0[5]  - q1.y)
                     + fabsf(fi0[6]  - q1.z) + fabsf(fi0[7]  - q1.w);
            float a2 = fabsf(fi0[8]  - q2.x) + fabsf(fi0[9]  - q2.y)
                     + fabsf(fi0[10] - q2.z) + fabsf(fi0[11] - q2.w);
            float a3 = fabsf(fi0[12] - q3.x) + fabsf(fi0[13] - q3.y)
                     + fabsf(fi0[14] - q3.z) + fabsf(fi0[15] - q3.w);
            e0 = exp2_fast(-((a0 + a1) + (a2 + a3)));
        }
        {
            float b0 = fabsf(fi1[0]  - q0.x) + fabsf(fi1[1]  - q0.y)
                     + fabsf(fi1[2]  - q0.z) + fabsf(fi1[3]  - q0.w);
            float b1 = fabsf(fi1[4]  - q1.x) + fabsf(fi1[5]  - q1.y)
                     + fabsf(fi1[6]  - q1.z) + fabsf(fi1[7]  - q1.w);
            float b2 = fabsf(fi1[8]  - q2.x) + fabsf(fi1[9]  - q2.y)
                     + fabsf(fi1[10] - q2.z) + fabsf(fi1[11] - q2.w);
            float b3 = fabsf(fi1[12] - q3.x) + fabsf(fi1[13] - q3.y)
                     + fabsf(fi1[14] - q3.z) + fabsf(fi1[15] - q3.w);
            e1 = exp2_fast(-((b0 + b1) + (b2 + b3)));
        }
        acc0 += e0;
        acc1 += e1;
        colacc[jj] = e0 + e1;   // per-j partial (over this lane's 2 i's)
    }

    // col sums (off-diag only): 64-lane butterfly per j, lane 0 stages to LDS
    if (offdiag) {
        #pragma unroll
        for (int jj = 0; jj < 16; ++jj) {
            float s = colacc[jj];
            s += __shfl_xor(s, 32);
            s += __shfl_xor(s, 16);
            s += __shfl_xor(s, 8);
            s += __shfl_xor(s, 4);
            s += __shfl_xor(s, 2);
            s += __shfl_xor(s, 1);
            if (lane == 0) colLds[wv * 16 + jj] = s;
        }
    }
    part[wv][lane]      = acc0;
    part[wv][lane + 64] = acc1;
    __syncthreads();

    if (tid < 128) {
        float s = ((part[0][tid] + part[1][tid]) + (part[2][tid] + part[3][tid]))
                + ((part[4][tid] + part[5][tid]) + (part[6][tid] + part[7][tid]));
        atomicAdd(&out[(size_t)(ti * 128 + tid) * OUTC + INS + k], s);
        if (offdiag)
            atomicAdd(&out[(size_t)(tj * 128 + tid) * OUTC + INS + k], colLds[tid]);
    }
}

extern "C" void kernel_launch(void* const* d_in, const int* in_sizes, int n_in,
                              void* d_out, int out_size, void* d_ws, size_t ws_size,
                              hipStream_t stream) {
    const float* x    = (const float*)d_in[0];
    const float* W    = (const float*)d_in[1];
    const float* bias = (const float*)d_in[2];
    float* out = (float*)d_out;

    // workspace layout (5 MB total):
    // [0, 2MB)   featT  [64][512][16] fp32
    // [2, 2.5MB) xh     [512][512] bf16
    // [2.5, 3MB) xl
    // [3, 4MB)   wh     [1024][512] bf16
    // [4, 5MB)   wl
    float* featT = (float*)d_ws;
    unsigned short* xh = (unsigned short*)((char*)d_ws + (size_t)(2 << 20));
    unsigned short* xl = xh + (size_t)NPTS * INS;
    unsigned short* wh = xl + (size_t)NPTS * INS;
    unsigned short* wl = wh + (size_t)CDIM * INS;

    convert_kernel<<<dim3(1056), 256, 0, stream>>>(x, W, out, xh, xl, wh, wl);
    gemm_mfma_kernel<<<dim3(CDIM / BN, NPTS / BM), 256, 0, stream>>>(
        xh, xl, wh, wl, bias, featT);
    pairwise_kernel<<<dim3(KDIM, 10), 512, 0, stream>>>(featT, out);
}

// Round 4
// 88.894 us; speedup vs baseline: 1.0991x; 1.0133x over previous
//
#include <hip/hip_runtime.h>

#define NPTS 512      // N rows
#define INS  512      // INSIZE
#define KDIM 64       // K groups
#define DDIM 16       // D per group
#define CDIM (KDIM*DDIM)  // 1024 output cols of the linear
#define OUTC (INS + KDIM) // 576

typedef __attribute__((ext_vector_type(4))) float f32x4;
typedef __attribute__((ext_vector_type(2))) float f32x2;
typedef __attribute__((ext_vector_type(8))) short short8v;      // 8 bf16 MFMA frag
typedef __attribute__((ext_vector_type(4))) unsigned short u16x4;
typedef __attribute__((ext_vector_type(8))) unsigned short u16x8;

__device__ __forceinline__ float exp2_fast(float x) {
    return __builtin_amdgcn_exp2f(x);
}

// packed f32 subtract: d = a - b, one VALU op for 2 lanes of data.
// a is per-lane (VGPR pair); b is wave-uniform (SGPR pair, legal VOP3P src1).
__device__ __forceinline__ f32x2 pk_sub_vs(f32x2 a, f32x2 b) {
    f32x2 d;
    asm("v_pk_add_f32 %0, %1, %2 neg_lo:[0,1] neg_hi:[0,1]"
        : "=v"(d) : "v"(a), "s"(b));
    return d;
}

// fp32 -> bf16 round-to-nearest-even
__device__ __forceinline__ unsigned short f2bf_rne(float f) {
    unsigned u = __float_as_uint(f);
    u += 0x7FFF + ((u >> 16) & 1);
    return (unsigned short)(u >> 16);
}
__device__ __forceinline__ float bf2f(unsigned short h) {
    return __uint_as_float(((unsigned)h) << 16);
}

// ---------------- Kernel 0: bf16 hi/lo split of x,W + out[:, :512] = x.
// b <  256 : x  -> xh, xl          (65536 float4)
// b <  768 : W  -> wh, wl          (131072 float4)
// b < 1024 : out[:, :512] = x      (65536 float4)
// (o_b init no longer needed: diag tiles write s-1 directly)
__global__ __launch_bounds__(256) void convert_kernel(
    const float* __restrict__ x, const float* __restrict__ W,
    float* __restrict__ out,
    unsigned short* __restrict__ xh, unsigned short* __restrict__ xl,
    unsigned short* __restrict__ wh, unsigned short* __restrict__ wl)
{
    const int b = blockIdx.x;
    const int tid = threadIdx.x;
    if (b < 768) {
        const int gid = b * 256 + tid;
        const float4* src;
        unsigned short *dh, *dl;
        int idx;
        if (gid < NPTS * INS / 4) {
            src = (const float4*)x; idx = gid; dh = xh; dl = xl;
        } else {
            src = (const float4*)W; idx = gid - NPTS * INS / 4; dh = wh; dl = wl;
        }
        float4 v = src[idx];
        u16x4 hv, lv;
        hv[0] = f2bf_rne(v.x); lv[0] = f2bf_rne(v.x - bf2f(hv[0]));
        hv[1] = f2bf_rne(v.y); lv[1] = f2bf_rne(v.y - bf2f(hv[1]));
        hv[2] = f2bf_rne(v.z); lv[2] = f2bf_rne(v.z - bf2f(hv[2]));
        hv[3] = f2bf_rne(v.w); lv[3] = f2bf_rne(v.w - bf2f(hv[3]));
        *(u16x4*)&dh[idx * 4] = hv;
        *(u16x4*)&dl[idx * 4] = lv;
    } else {
        const int idx = (b - 768) * 256 + tid;   // 0 .. 65535
        const int i  = idx >> 7;                 // /128
        const int j4 = idx & 127;
        ((float4*)out)[i * (OUTC / 4) + j4] = ((const float4*)x)[i * (INS / 4) + j4];
    }
}

// ---------------- Kernel A: split-bf16 MFMA GEMM, full K=512.
// acc = xh*Wh + xh*Wl + xl*Wh  (lo*lo dropped).
// Tile 32i x 64c, grid 16x16 = 256 blocks (1/CU). 4 waves: 2(m) x 2(n).
// A-fragments loaded DIRECTLY from global (L2-resident, same k-slot bijection
// as LDS-staged B) -> LDS reads 6->4 per wave-kt, no A staging/stores.
// LDK=40: B frag ds_read_b128 bank-quad (5*row+g)%8 -> conflict-free.
#define BM 32
#define BN 64
#define BK 32
#define LDK 40

__global__ __launch_bounds__(256) void gemm_mfma_kernel(
    const unsigned short* __restrict__ xh, const unsigned short* __restrict__ xl,
    const unsigned short* __restrict__ wh, const unsigned short* __restrict__ wl,
    const float* __restrict__ bias,
    float* __restrict__ featT)      // [64][512][16]
{
    __shared__ unsigned short Bh[BN * LDK], Bl[BN * LDK];

    const int tid   = threadIdx.x;
    const int cbase = blockIdx.x * BN;   // 16 c-tiles
    const int ibase = blockIdx.y * BM;   // 16 i-tiles

    const int lane = tid & 63;
    const int wv   = tid >> 6;
    const int wm   = wv >> 1;            // wave row 0..1 (16 i each)
    const int wn   = wv & 1;             // wave col 0..1 (32 c each)

    // B staging: row = tid>>2 (0..63), k-chunk = (tid&3)*8
    const int brow = tid >> 2;
    const int kg   = tid & 3;
    const size_t gB0 = (size_t)(cbase + brow) * INS + kg * 8;
    const int bloff = brow * LDK + kg * 8;

    // fragment addressing (A/B share the k-slot bijection -> k-grouping cancels)
    const int frow = lane & 15;
    const int fg   = lane >> 4;
    const size_t aGlob = (size_t)(ibase + wm * 16 + frow) * INS + fg * 8;
    const int boff = (wn * 32 + frow) * LDK + fg * 8;

    f32x4 acc[2] = {};

    // prefetched registers for tile 0
    u16x8 a_h = *(const u16x8*)&xh[aGlob];
    u16x8 a_l = *(const u16x8*)&xl[aGlob];
    u16x8 rbh = *(const u16x8*)&wh[gB0];
    u16x8 rbl = *(const u16x8*)&wl[gB0];

    for (int kt = 0; kt < INS / BK; ++kt) {
        __syncthreads();   // previous tile's frag reads done
        *(u16x8*)&Bh[bloff] = rbh;
        *(u16x8*)&Bl[bloff] = rbl;
        __syncthreads();

        u16x8 a_h2, a_l2;
        {
            const int ktn = (kt + 1) & 15;           // clamp wraps; values unused at kt=15
            const size_t oa = (size_t)ktn * BK;
            a_h2 = *(const u16x8*)&xh[aGlob + oa];
            a_l2 = *(const u16x8*)&xl[aGlob + oa];
            if (kt + 1 < INS / BK) {
                const size_t o = (size_t)(kt + 1) * BK;
                rbh = *(const u16x8*)&wh[gB0 + o];
                rbl = *(const u16x8*)&wl[gB0 + o];
            }
        }

        #pragma unroll
        for (int n = 0; n < 2; ++n) {
            short8v bv_h = *(const short8v*)&Bh[boff + n * 16 * LDK];
            short8v bv_l = *(const short8v*)&Bl[boff + n * 16 * LDK];
            short8v av_h = (short8v)a_h;
            short8v av_l = (short8v)a_l;
            acc[n] = __builtin_amdgcn_mfma_f32_16x16x32_bf16(av_h, bv_h, acc[n], 0, 0, 0);
            acc[n] = __builtin_amdgcn_mfma_f32_16x16x32_bf16(av_h, bv_l, acc[n], 0, 0, 0);
            acc[n] = __builtin_amdgcn_mfma_f32_16x16x32_bf16(av_l, bv_h, acc[n], 0, 0, 0);
        }
        a_h = a_h2;
        a_l = a_l2;
    }

    // epilogue: C/D layout col=lane&15 (c-dim), row=(lane>>4)*4+r (i-dim)  [HW-verified]
    const float LOG2E = 1.4426950408889634f;
    const int r0 = (lane >> 4) * 4;
    const int i0 = ibase + wm * 16 + r0;
    #pragma unroll
    for (int n = 0; n < 2; ++n) {
        const int c  = cbase + wn * 32 + n * 16 + (lane & 15);
        const float bv = bias[c];
        const int kk = c >> 4;
        const int d  = c & 15;
        float* dst = featT + (size_t)kk * NPTS * DDIM + d;
        #pragma unroll
        for (int r = 0; r < 4; ++r) {
            dst[(size_t)(i0 + r) * DDIM] = (acc[n][r] + bv) * LOG2E;
        }
    }
}

// ---------------- Kernel C: o_b via SYMMETRIC triangular tiling.
// Grid (64 k, 10 tiles) x 512 thr. 128x128 tiles over (i,j):
//   tz 0..3 : diagonal (ti==tj), full tile, row sums only (written as s-1:
//             the exact-diagonal exp2(0)=1 is removed here, no init pass).
//   tz 4..9 : off-diagonal (ti<tj), each e_ij computed ONCE:
//             row sum in-lane; col sums via LDS-transpose reduction
//             (16 ds_write_b32/lane + 4 ds_read_b128/thread -- replaces the
//             96-shfl butterfly that was ~2.4us of LDS-pipe time).
// Inner loop: v_pk_add_f32 packed subtract (fi in VGPR, wave-uniform q in SGPR)
// -> 25 VALU/eval instead of 33.
__global__ __launch_bounds__(512) void pairwise_kernel(
    const float* __restrict__ f, float* __restrict__ out)   // out [512][576]
{
    const int k  = blockIdx.x;   // 64
    const int tz = blockIdx.y;   // 10
    const int ti = (int)((0x2110003210ULL >> (4 * tz)) & 0xF);
    const int tj = (int)((0x3323213210ULL >> (4 * tz)) & 0xF);
    const bool offdiag = (tz >= 4);

    __shared__ float part[8][128];
    __shared__ float colT[128][68];   // [j-slot][lane partials], stride 68 breaks conflicts

    const int tid  = threadIdx.x;
    const int lane = tid & 63;
    const int wv   = __builtin_amdgcn_readfirstlane(tid >> 6);  // 0..7, SGPR
    const int i0   = ti * 128 + lane;
    const int i1   = i0 + 64;

    f32x2 fi0[8], fi1[8];
    {
        const float4* p0 = (const float4*)(f + ((size_t)k * NPTS + i0) * DDIM);
        const float4* p1 = (const float4*)(f + ((size_t)k * NPTS + i1) * DDIM);
        #pragma unroll
        for (int q = 0; q < 4; ++q) {
            float4 a = p0[q];
            fi0[q * 2 + 0] = f32x2{a.x, a.y};
            fi0[q * 2 + 1] = f32x2{a.z, a.w};
            float4 b = p1[q];
            fi1[q * 2 + 0] = f32x2{b.x, b.y};
            fi1[q * 2 + 1] = f32x2{b.z, b.w};
        }
    }

    // wave-uniform j-row pointer: 16 j's per wave
    const float* __restrict__ jrow = f + ((size_t)k * NPTS + tj * 128 + wv * 16) * DDIM;

    float acc0 = 0.f, acc1 = 0.f;
    float colacc[16];
    #pragma unroll
    for (int jj = 0; jj < 16; ++jj) {
        const float* p = jrow + jj * DDIM;   // uniform address -> SMEM loads
        float4 q0 = *(const float4*)(p);
        float4 q1 = *(const float4*)(p + 4);
        float4 q2 = *(const float4*)(p + 8);
        float4 q3 = *(const float4*)(p + 12);
        f32x2 qv[8];
        qv[0] = f32x2{q0.x, q0.y}; qv[1] = f32x2{q0.z, q0.w};
        qv[2] = f32x2{q1.x, q1.y}; qv[3] = f32x2{q1.z, q1.w};
        qv[4] = f32x2{q2.x, q2.y}; qv[5] = f32x2{q2.z, q2.w};
        qv[6] = f32x2{q3.x, q3.y}; qv[7] = f32x2{q3.z, q3.w};

        float s0, s1;
        {
            float t[8];
            #pragma unroll
            for (int u = 0; u < 8; ++u) {
                f32x2 d = pk_sub_vs(fi0[u], qv[u]);
                t[u] = fabsf(d.x) + fabsf(d.y);
            }
            s0 = (((t[0] + t[1]) + (t[2] + t[3])) + ((t[4] + t[5]) + (t[6] + t[7])));
        }
        {
            float t[8];
            #pragma unroll
            for (int u = 0; u < 8; ++u) {
                f32x2 d = pk_sub_vs(fi1[u], qv[u]);
                t[u] = fabsf(d.x) + fabsf(d.y);
            }
            s1 = (((t[0] + t[1]) + (t[2] + t[3])) + ((t[4] + t[5]) + (t[6] + t[7])));
        }
        float e0 = exp2_fast(-s0);
        float e1 = exp2_fast(-s1);
        acc0 += e0;
        acc1 += e1;
        colacc[jj] = e0 + e1;   // per-j partial (this lane's 2 i's)
    }

    if (offdiag) {
        #pragma unroll
        for (int jj = 0; jj < 16; ++jj)
            colT[wv * 16 + jj][lane] = colacc[jj];
    }
    part[wv][lane]      = acc0;
    part[wv][lane + 64] = acc1;
    __syncthreads();

    // row sums: one value per i, diag tiles subtract the exact diagonal term.
    if (tid < 128) {
        float s = ((part[0][tid] + part[1][tid]) + (part[2][tid] + part[3][tid]))
                + ((part[4][tid] + part[5][tid]) + (part[6][tid] + part[7][tid]));
        if (!offdiag) s -= 1.0f;
        atomicAdd(&out[(size_t)(ti * 128 + tid) * OUTC + INS + k], s);
    }
    // col sums: 4 threads per j-slot, 16 f32 each, 2-step shfl within quad.
    if (offdiag) {
        const int slot = tid >> 2;       // 0..127
        const int qq   = tid & 3;
        const float* cp = &colT[slot][qq * 16];
        float4 u0 = *(const float4*)(cp);
        float4 u1 = *(const float4*)(cp + 4);
        float4 u2 = *(const float4*)(cp + 8);
        float4 u3 = *(const float4*)(cp + 12);
        float s = (((u0.x + u0.y) + (u0.z + u0.w)) + ((u1.x + u1.y) + (u1.z + u1.w)))
                + (((u2.x + u2.y) + (u2.z + u2.w)) + ((u3.x + u3.y) + (u3.z + u3.w)));
        s += __shfl_xor(s, 1);
        s += __shfl_xor(s, 2);
        if (qq == 0)
            atomicAdd(&out[(size_t)(tj * 128 + slot) * OUTC + INS + k], s);
    }
}

extern "C" void kernel_launch(void* const* d_in, const int* in_sizes, int n_in,
                              void* d_out, int out_size, void* d_ws, size_t ws_size,
                              hipStream_t stream) {
    const float* x    = (const float*)d_in[0];
    const float* W    = (const float*)d_in[1];
    const float* bias = (const float*)d_in[2];
    float* out = (float*)d_out;

    // workspace layout (5 MB total):
    // [0, 2MB)   featT  [64][512][16] fp32
    // [2, 2.5MB) xh     [512][512] bf16
    // [2.5, 3MB) xl
    // [3, 4MB)   wh     [1024][512] bf16
    // [4, 5MB)   wl
    float* featT = (float*)d_ws;
    unsigned short* xh = (unsigned short*)((char*)d_ws + (size_t)(2 << 20));
    unsigned short* xl = xh + (size_t)NPTS * INS;
    unsigned short* wh = xl + (size_t)NPTS * INS;
    unsigned short* wl = wh + (size_t)CDIM * INS;

    convert_kernel<<<dim3(1024), 256, 0, stream>>>(x, W, out, xh, xl, wh, wl);
    gemm_mfma_kernel<<<dim3(CDIM / BN, NPTS / BM), 256, 0, stream>>>(
        xh, xl, wh, wl, bias, featT);
    pairwise_kernel<<<dim3(KDIM, 10), 512, 0, stream>>>(featT, out);
}